// Round 18
// baseline (80.033 us; speedup 1.0000x reference)
//
#include <hip/hip_runtime.h>
#include <hip/hip_bf16.h>
#include <math.h>

#define B_ 2
#define C_ 64
#define H_ 192
#define W_ 192
#define HW_ (H_*W_)
#define BHW_ (B_*HW_)
#define KK_ 9
#define CK_ (C_*KK_)      // 576
#define KSTEPS_ (CK_/32)  // 18
#define TX_ 12            // W_/16 column tiles
#define WROWS_ 6          // dc window rows (h0-2 .. h0+3)
#define WCOLS_ 21         // dc window cols (w0-2 .. w0+18)
#define WCHUNKS_ (WROWS_*WCOLS_*8)     // 1008
#define FWROWS_ 4         // fuse window rows (h0-1 .. h0+2)
#define FWCOLS_ 18        // fuse window cols (w0-1 .. w0+16)
#define FWCHUNKS_ (FWROWS_*FWCOLS_*8)  // 576

typedef __bf16 bf16x8 __attribute__((ext_vector_type(8)));
typedef float  f32x4  __attribute__((ext_vector_type(4)));
typedef unsigned short ushortx8 __attribute__((ext_vector_type(8)));
typedef unsigned short ushortx4 __attribute__((ext_vector_type(4)));

__device__ __forceinline__ float bf2f(unsigned short u) {
    unsigned int t = ((unsigned int)u) << 16;
    return __builtin_bit_cast(float, t);
}
__device__ __forceinline__ unsigned short f2bf(float f) {
    __hip_bfloat16 hb = __float2bfloat16(f);
    return *reinterpret_cast<unsigned short*>(&hb);
}

// ---------------- LayerNorm (288 blocks) + weight prepack (36 blocks) ------
__global__ void ln_prepack_kernel(const float* __restrict__ x,
                                  const float* __restrict__ lnw,
                                  const float* __restrict__ lnb,
                                  unsigned short* __restrict__ xnb,
                                  const float* __restrict__ dw,
                                  const float* __restrict__ fw,
                                  const float* __restrict__ offw,
                                  const float* __restrict__ maskw,
                                  unsigned short* __restrict__ wpack,
                                  unsigned short* __restrict__ wpf,
                                  unsigned short* __restrict__ wpc) {
    if (blockIdx.x < 288) {
        int p = blockIdx.x * 256 + threadIdx.x;
        int b = p / HW_, pix = p % HW_;
        const float* xb = x + (size_t)b * C_ * HW_ + pix;
        float v[C_];
        float s = 0.f, s2 = 0.f;
        #pragma unroll
        for (int c = 0; c < C_; ++c) {
            v[c] = xb[(size_t)c * HW_];
            s += v[c]; s2 += v[c] * v[c];
        }
        float mu  = s * (1.0f / C_);
        float var = s2 * (1.0f / C_) - mu * mu;
        float inv = rsqrtf(var + 1e-5f);
        unsigned short* zb = xnb + (size_t)p * 64;
        #pragma unroll
        for (int g = 0; g < 8; ++g) {
            ushortx8 st;
            #pragma unroll
            for (int j = 0; j < 8; ++j) {
                int c = g * 8 + j;
                st[j] = f2bf((v[c] - mu) * inv * lnw[c] + lnb[c]);
            }
            *reinterpret_cast<ushortx8*>(zb + g * 8) = st;
        }
        return;
    }
    const int n1 = 4 * KSTEPS_ * 64 * 8;
    const int n2 = 4 * KSTEPS_ * 64 * 8;
    const int n3 = 2 * KSTEPS_ * 64 * 8;
    int gid = (blockIdx.x - 288) * 256 + threadIdx.x;
    int nth = 36 * 256;
    for (int idx = gid; idx < n1 + n2 + n3; idx += nth) {
        int which = (idx < n1) ? 0 : (idx < n1 + n2 ? 1 : 2);
        int rem = idx - (which == 0 ? 0 : (which == 1 ? n1 : n1 + n2));
        int j = rem & 7;
        int l = (rem >> 3) & 63;
        int rest = rem >> 9;
        int s = rest % KSTEPS_;
        int t = rest / KSTEPS_;
        int oc = t * 16 + (l & 15);
        int ck = s * 32 + (l >> 4) * 8 + j;
        int k = ck >> 6, c = ck & 63;
        float v;
        if (which == 0) {
            v = dw[(size_t)oc * CK_ + c * 9 + k];
        } else if (which == 1) {
            v = fw[(size_t)oc * CK_ + c * 9 + k];
        } else {
            v = (oc < 18) ? offw[(size_t)oc * CK_ + c * 9 + k]
              : (oc < 27) ? maskw[(size_t)(oc - 18) * CK_ + c * 9 + k]
              : 0.f;
        }
        unsigned short u = f2bf(v);
        if (which == 0) wpack[rem] = u;
        else if (which == 1) wpf[rem] = u;
        else wpc[rem] = u;
    }
}

// ---------------- merged conv27 + deformable conv ---------------------------
// R17 structure + s_setprio(1) around MFMA clusters (T5: phase-split waves).
__global__ void __launch_bounds__(128) dc_mfma(
        const unsigned short* __restrict__ xnb,   // NHWC
        const unsigned short* __restrict__ wpc,
        const float* __restrict__ offb, const float* __restrict__ maskb,
        const unsigned short* __restrict__ wpack,
        const float* __restrict__ db,
        unsigned short* __restrict__ xdefb) {     // NHWC
    __shared__ ushortx8 win[WCHUNKS_];           // 16128 B (reused as exchange)
    __shared__ alignas(16) float som[32][32];    // 4096 B, rotated columns
    int tid  = threadIdx.x;
    int wave = tid >> 6;
    int lane = tid & 63;
    int bid  = blockIdx.x;
    int rg   = bid % (H_ / 2);
    int rest = bid / (H_ / 2);
    int tx   = rest % TX_;
    int b    = rest / TX_;
    int pq = lane & 15;
    int kchunk = lane >> 4;
    int h0 = rg * 2;
    int w0 = tx * 16, w = w0 + pq;
    int rot = (pq & 7) * 4;

    const unsigned short* xb = xnb + (size_t)b * HW_ * 64;

    // ---- stage shared window rows h0-2..h0+3, cols w0-2..w0+18 ----
    #pragma unroll
    for (int i = 0; i < 8; ++i) {
        int idx = i * 128 + tid;
        if (idx < WCHUNKS_) {
            int r    = idx / (WCOLS_ * 8);
            int rem2 = idx - r * (WCOLS_ * 8);
            int c    = rem2 >> 3;
            int seg  = rem2 & 7;
            int gy = min(max(h0 - 2 + r, 0), H_ - 1);
            int gx = min(max(w0 - 2 + c, 0), W_ - 1);
            ushortx8 v = *reinterpret_cast<const ushortx8*>(
                xb + ((size_t)(gy * W_ + gx) * 64 + seg * 8));
            win[(r * WCOLS_ + c) * 8 + (seg ^ (c & 7))] = v;
        }
    }
    __syncthreads();

    // ---- phase 1: conv27, row-split (wave w -> row h0+w, full K) ----
    {
        int hp = h0 + wave;
        f32x4 cacc[2];
        cacc[0] = f32x4{0.f, 0.f, 0.f, 0.f};
        cacc[1] = f32x4{0.f, 0.f, 0.f, 0.f};
        #pragma unroll
        for (int s = 0; s < KSTEPS_; ++s) {
            const int k = s >> 1;
            const int dy = k / 3 - 1, dxk = k % 3 - 1;
            int wc = pq + dxk + 2;
            int sidx = ((s & 1) * 4 + kchunk) ^ (wc & 7);
            bool ok = ((unsigned)(hp + dy) < (unsigned)H_) &&
                      ((unsigned)(w + dxk) < (unsigned)W_);
            int wr = wave + dy + 2;
            ushortx8 u = win[(wr * WCOLS_ + wc) * 8 + sidx];
            if (!ok) u = ushortx8{0, 0, 0, 0, 0, 0, 0, 0};
            bf16x8 bv = __builtin_bit_cast(bf16x8, u);
            __builtin_amdgcn_s_setprio(1);
            #pragma unroll
            for (int t = 0; t < 2; ++t) {
                bf16x8 afrag = *reinterpret_cast<const bf16x8*>(
                    wpc + ((size_t)(t * KSTEPS_ + s) * 64 + lane) * 8);
                cacc[t] = __builtin_amdgcn_mfma_f32_16x16x32_bf16(afrag, bv, cacc[t], 0, 0, 0);
            }
            __builtin_amdgcn_s_setprio(0);
        }
        // bias / sigmoid -> som transpose slice (rotated columns)
        #pragma unroll
        for (int t = 0; t < 2; ++t) {
            f32x4 sv;
            #pragma unroll
            for (int r = 0; r < 4; ++r) {
                int oc = t * 16 + kchunk * 4 + r;
                float a = cacc[t][r];
                if (oc < 18)      sv[r] = a + offb[oc];
                else if (oc < 27) sv[r] = 1.f / (1.f + expf(-(a + maskb[oc - 18])));
                else              sv[r] = 0.f;
            }
            int col = (t * 16 + kchunk * 4 + rot) & 31;
            *reinterpret_cast<f32x4*>(&som[wave * 16 + pq][col]) = sv;
        }
    }
    __syncthreads();

    // ---- phase 2: quarter-balanced tap split, straight-line tapbody ----
    f32x4 acc[2][4];
    #pragma unroll
    for (int pg = 0; pg < 2; ++pg)
        #pragma unroll
        for (int t = 0; t < 4; ++t) acc[pg][t] = f32x4{0.f, 0.f, 0.f, 0.f};

    auto taprow = [&](int k, int pg) {
        int hp = h0 + pg;
        const float* om = som[pg * 16 + pq];
        float dy = om[(2 * k + rot) & 31];
        float dx = om[(2 * k + 1 + rot) & 31];
        float m  = om[(18 + k + rot) & 31];
        float py = dy + (float)(hp - 1 + k / 3);
        float px = dx + (float)(w - 1 + k % 3);
        float fy = floorf(py), fx = floorf(px);
        float ly = py - fy, lx = px - fx;
        int y0 = (int)fy, x0 = (int)fx;
        int y1 = y0 + 1, x1 = x0 + 1;
        bool oky0 = (unsigned)y0 < (unsigned)H_;
        bool oky1 = (unsigned)y1 < (unsigned)H_;
        bool okx0 = (unsigned)x0 < (unsigned)W_;
        bool okx1 = (unsigned)x1 < (unsigned)W_;
        float q[4];
        q[0] = (oky0 && okx0) ? (1.f - ly) * (1.f - lx) * m : 0.f;
        q[1] = (oky0 && okx1) ? (1.f - ly) * lx * m : 0.f;
        q[2] = (oky1 && okx0) ? ly * (1.f - lx) * m : 0.f;
        q[3] = (oky1 && okx1) ? ly * lx * m : 0.f;
        int wr0 = y0 - (h0 - 2), wr1 = y1 - (h0 - 2);
        int wc0 = x0 - (w0 - 2), wc1 = x1 - (w0 - 2);
        bool inr0 = (unsigned)wr0 < (unsigned)WROWS_;
        bool inr1 = (unsigned)wr1 < (unsigned)WROWS_;
        bool inc0 = (unsigned)wc0 < (unsigned)WCOLS_;
        bool inc1 = (unsigned)wc1 < (unsigned)WCOLS_;
        bool in[4];
        in[0] = inr0 && inc0; in[1] = inr0 && inc1;
        in[2] = inr1 && inc0; in[3] = inr1 && inc1;
        int swr0 = min(max(wr0, 0), WROWS_ - 1), swr1 = min(max(wr1, 0), WROWS_ - 1);
        int swc0 = min(max(wc0, 0), WCOLS_ - 1), swc1 = min(max(wc1, 0), WCOLS_ - 1);
        int cb[4], sx[4];
        cb[0] = (swr0 * WCOLS_ + swc0) * 8; sx[0] = swc0 & 7;
        cb[1] = (swr0 * WCOLS_ + swc1) * 8; sx[1] = swc1 & 7;
        cb[2] = (swr1 * WCOLS_ + swc0) * 8; sx[2] = swc0 & 7;
        cb[3] = (swr1 * WCOLS_ + swc1) * 8; sx[3] = swc1 & 7;
        int cy0 = min(max(y0, 0), H_ - 1), cy1 = min(max(y1, 0), H_ - 1);
        int cx0 = min(max(x0, 0), W_ - 1), cx1 = min(max(x1, 0), W_ - 1);
        int ga[4];
        ga[0] = cy0 * W_ + cx0; ga[1] = cy0 * W_ + cx1;
        ga[2] = cy1 * W_ + cx0; ga[3] = cy1 * W_ + cx1;

        #pragma unroll
        for (int half = 0; half < 2; ++half) {
            int s = k * 2 + half;
            int seg = half * 4 + kchunk;
            int cbg = half * 32 + kchunk * 8;
            ushortx8 v[4];
            #pragma unroll
            for (int c = 0; c < 4; ++c) v[c] = win[cb[c] + (seg ^ sx[c])];
            #pragma unroll
            for (int c = 0; c < 4; ++c)
                if (q[c] != 0.f && !in[c])
                    v[c] = *reinterpret_cast<const ushortx8*>(
                        xb + ((size_t)ga[c] * 64 + cbg));
            union { unsigned short u[8]; bf16x8 v; } bu;
            #pragma unroll
            for (int j = 0; j < 8; ++j) {
                float a = q[0] * bf2f(v[0][j]) + q[1] * bf2f(v[1][j])
                        + q[2] * bf2f(v[2][j]) + q[3] * bf2f(v[3][j]);
                bu.u[j] = f2bf(a);
            }
            __builtin_amdgcn_s_setprio(1);
            #pragma unroll
            for (int t = 0; t < 4; ++t) {
                bf16x8 afr = *reinterpret_cast<const bf16x8*>(
                    wpack + ((size_t)(t * KSTEPS_ + s) * 64 + lane) * 8);
                acc[pg][t] = __builtin_amdgcn_mfma_f32_16x16x32_bf16(
                    afr, bu.v, acc[pg][t], 0, 0, 0);
            }
            __builtin_amdgcn_s_setprio(0);
        }
    };

    if (wave == 0) {
        taprow(0, 0); taprow(0, 1);
        taprow(1, 0); taprow(1, 1);
        taprow(2, 0); taprow(2, 1);
        taprow(3, 0); taprow(3, 1);
        taprow(4, 0);
    } else {
        taprow(4, 1);
        taprow(5, 0); taprow(5, 1);
        taprow(6, 0); taprow(6, 1);
        taprow(7, 0); taprow(7, 1);
        taprow(8, 0); taprow(8, 1);
    }

    // ---- cross-wave accumulator exchange (win reused; 17-pad) ----
    __syncthreads();
    float* red = reinterpret_cast<float*>(win);
    {
        float* slot = red + (wave * 64 + lane) * 17;
        if (wave == 0) {
            #pragma unroll
            for (int t = 0; t < 4; ++t)
                #pragma unroll
                for (int r = 0; r < 4; ++r) slot[t * 4 + r] = acc[1][t][r];
        } else {
            #pragma unroll
            for (int t = 0; t < 4; ++t)
                #pragma unroll
                for (int r = 0; r < 4; ++r) slot[t * 4 + r] = acc[0][t][r];
        }
    }
    __syncthreads();
    {
        const float* pslot = red + ((1 - wave) * 64 + lane) * 17;
        int hp = h0 + wave;
        unsigned short* zb = xdefb + ((size_t)(b * HW_ + hp * W_ + w)) * 64;
        if (wave == 0) {
            #pragma unroll
            for (int t = 0; t < 4; ++t) {
                ushortx4 st;
                #pragma unroll
                for (int r = 0; r < 4; ++r) {
                    int oc = t * 16 + kchunk * 4 + r;
                    st[r] = f2bf(acc[0][t][r] + pslot[t * 4 + r] + db[oc]);
                }
                *reinterpret_cast<ushortx4*>(zb + t * 16 + kchunk * 4) = st;
            }
        } else {
            #pragma unroll
            for (int t = 0; t < 4; ++t) {
                ushortx4 st;
                #pragma unroll
                for (int r = 0; r < 4; ++r) {
                    int oc = t * 16 + kchunk * 4 + r;
                    st[r] = f2bf(acc[1][t][r] + pslot[t * 4 + r] + db[oc]);
                }
                *reinterpret_cast<ushortx4*>(zb + t * 16 + kchunk * 4) = st;
            }
        }
    }
}

// ---------------- fusion conv, K-split across 2 waves ----------------------
__global__ void __launch_bounds__(128) fuse_mfma(
        const unsigned short* __restrict__ xdefb,  // NHWC
        const unsigned short* __restrict__ wpf,
        const float* __restrict__ fb,
        const float* __restrict__ premask,
        const float* __restrict__ xin,             // NCHW
        float* __restrict__ out) {                 // NCHW
    __shared__ ushortx8 fwin[FWCHUNKS_];  // 9216 B (reused as exchange buf)
    int tid  = threadIdx.x;
    int wave = tid >> 6;
    int lane = tid & 63;
    int bid  = blockIdx.x;
    int rg   = bid % (H_ / 2);
    int rest = bid / (H_ / 2);
    int tx   = rest % TX_;
    int b    = rest / TX_;
    int pq = lane & 15;
    int kchunk = lane >> 4;
    int h0 = rg * 2;
    int w0 = tx * 16, w = w0 + pq;

    const unsigned short* xb = xdefb + (size_t)b * HW_ * 64;

    #pragma unroll
    for (int i = 0; i < 5; ++i) {
        int idx = i * 128 + tid;
        if (idx < FWCHUNKS_) {
            int r    = idx / (FWCOLS_ * 8);
            int rem2 = idx - r * (FWCOLS_ * 8);
            int c    = rem2 >> 3;
            int seg  = rem2 & 7;
            int gy = min(max(h0 - 1 + r, 0), H_ - 1);
            int gx = min(max(w0 - 1 + c, 0), W_ - 1);
            ushortx8 v = *reinterpret_cast<const ushortx8*>(
                xb + ((size_t)(gy * W_ + gx) * 64 + seg * 8));
            fwin[(r * FWCOLS_ + c) * 8 + (seg ^ (c & 7))] = v;
        }
    }
    __syncthreads();

    f32x4 acc[2][4];
    #pragma unroll
    for (int pg = 0; pg < 2; ++pg)
        #pragma unroll
        for (int t = 0; t < 4; ++t) acc[pg][t] = f32x4{0.f, 0.f, 0.f, 0.f};

    auto stepbody = [&](int s) {
        const int k = s >> 1;
        const int dy = k / 3 - 1, dxk = k % 3 - 1;
        int wc = pq + dxk + 1;
        int sidx = ((s & 1) * 4 + kchunk) ^ (wc & 7);
        bf16x8 af[4];
        #pragma unroll
        for (int t = 0; t < 4; ++t)
            af[t] = *reinterpret_cast<const bf16x8*>(
                wpf + ((size_t)(t * KSTEPS_ + s) * 64 + lane) * 8);
        bf16x8 bv[2];
        #pragma unroll
        for (int pg = 0; pg < 2; ++pg) {
            int hp = h0 + pg;
            bool ok = ((unsigned)(hp + dy) < (unsigned)H_) &&
                      ((unsigned)(w + dxk) < (unsigned)W_);
            int wr = pg + dy + 1;
            ushortx8 u = fwin[(wr * FWCOLS_ + wc) * 8 + sidx];
            if (!ok) u = ushortx8{0, 0, 0, 0, 0, 0, 0, 0};
            bv[pg] = __builtin_bit_cast(bf16x8, u);
        }
        __builtin_amdgcn_s_setprio(1);
        #pragma unroll
        for (int t = 0; t < 4; ++t) {
            acc[0][t] = __builtin_amdgcn_mfma_f32_16x16x32_bf16(af[t], bv[0], acc[0][t], 0, 0, 0);
            acc[1][t] = __builtin_amdgcn_mfma_f32_16x16x32_bf16(af[t], bv[1], acc[1][t], 0, 0, 0);
        }
        __builtin_amdgcn_s_setprio(0);
    };

    if (wave == 0) {
        stepbody(0); stepbody(1); stepbody(2); stepbody(3); stepbody(4);
        stepbody(5); stepbody(6); stepbody(7); stepbody(8);
    } else {
        stepbody(9); stepbody(10); stepbody(11); stepbody(12); stepbody(13);
        stepbody(14); stepbody(15); stepbody(16); stepbody(17);
    }

    __syncthreads();
    float* red = reinterpret_cast<float*>(fwin);
    {
        float* slot = red + (wave * 64 + lane) * 17;
        if (wave == 0) {
            #pragma unroll
            for (int t = 0; t < 4; ++t)
                #pragma unroll
                for (int r = 0; r < 4; ++r) slot[t * 4 + r] = acc[1][t][r];
        } else {
            #pragma unroll
            for (int t = 0; t < 4; ++t)
                #pragma unroll
                for (int r = 0; r < 4; ++r) slot[t * 4 + r] = acc[0][t][r];
        }
    }
    __syncthreads();
    {
        const float* pslot = red + ((1 - wave) * 64 + lane) * 17;
        int hp = h0 + wave;
        int pix = hp * W_ + w;
        float pm = premask[(size_t)b * HW_ + pix];
        if (wave == 0) {
            #pragma unroll
            for (int t = 0; t < 4; ++t) {
                #pragma unroll
                for (int r = 0; r < 4; ++r) {
                    int oc = t * 16 + kchunk * 4 + r;
                    size_t oidx = ((size_t)b * C_ + oc) * HW_ + pix;
                    float a = acc[0][t][r] + pslot[t * 4 + r] + fb[oc];
                    out[oidx] = a * pm + xin[oidx] * (1.f - pm);
                }
            }
        } else {
            #pragma unroll
            for (int t = 0; t < 4; ++t) {
                #pragma unroll
                for (int r = 0; r < 4; ++r) {
                    int oc = t * 16 + kchunk * 4 + r;
                    size_t oidx = ((size_t)b * C_ + oc) * HW_ + pix;
                    float a = acc[1][t][r] + pslot[t * 4 + r] + fb[oc];
                    out[oidx] = a * pm + xin[oidx] * (1.f - pm);
                }
            }
        }
    }
}

extern "C" void kernel_launch(void* const* d_in, const int* in_sizes, int n_in,
                              void* d_out, int out_size, void* d_ws, size_t ws_size,
                              hipStream_t stream) {
    const float* x       = (const float*)d_in[0];
    const float* premask = (const float*)d_in[1];
    const float* lnw     = (const float*)d_in[2];
    const float* lnb     = (const float*)d_in[3];
    const float* offw    = (const float*)d_in[4];
    const float* offb    = (const float*)d_in[5];
    const float* maskw   = (const float*)d_in[6];
    const float* maskb   = (const float*)d_in[7];
    const float* dw      = (const float*)d_in[8];
    const float* db      = (const float*)d_in[9];
    const float* fw      = (const float*)d_in[10];
    const float* fb      = (const float*)d_in[11];
    float* out = (float*)d_out;

    char* ws = (char*)d_ws;
    unsigned short* xnb   = (unsigned short*)ws;  ws += sizeof(short) * (size_t)BHW_ * 64;
    unsigned short* xdefb = (unsigned short*)ws;  ws += sizeof(short) * (size_t)BHW_ * 64;
    unsigned short* wpack = (unsigned short*)ws;  ws += sizeof(short) * 4 * KSTEPS_ * 64 * 8;
    unsigned short* wpf   = (unsigned short*)ws;  ws += sizeof(short) * 4 * KSTEPS_ * 64 * 8;
    unsigned short* wpc   = (unsigned short*)ws;  ws += sizeof(short) * 2 * KSTEPS_ * 64 * 8;

    const int grid = B_ * TX_ * (H_ / 2);   // 2304 two-wave blocks

    ln_prepack_kernel<<<288 + 36, 256, 0, stream>>>(
        x, lnw, lnb, xnb, dw, fw, offw, maskw, wpack, wpf, wpc);
    dc_mfma<<<grid, 128, 0, stream>>>(
        xnb, wpc, offb, maskb, wpack, db, xdefb);
    fuse_mfma<<<grid, 128, 0, stream>>>(xdefb, wpf, fb, premask, x, out);
}

// Round 19
// 72.022 us; speedup vs baseline: 1.1112x; 1.1112x over previous
//
#include <hip/hip_runtime.h>
#include <hip/hip_bf16.h>
#include <math.h>

#define B_ 2
#define C_ 64
#define H_ 192
#define W_ 192
#define HW_ (H_*W_)
#define BHW_ (B_*HW_)
#define KK_ 9
#define CK_ (C_*KK_)      // 576
#define KSTEPS_ (CK_/32)  // 18
#define TX_ 12            // W_/16 column tiles
#define WROWS_ 6          // dc window rows (h0-2 .. h0+3)
#define WCOLS_ 21         // dc window cols (w0-2 .. w0+18)
#define WCHUNKS_ (WROWS_*WCOLS_*8)     // 1008
#define FWROWS_ 4         // fuse window rows (h0-1 .. h0+2)
#define FWCOLS_ 18        // fuse window cols (w0-1 .. w0+16)
#define FWCHUNKS_ (FWROWS_*FWCOLS_*8)  // 576

typedef __bf16 bf16x8 __attribute__((ext_vector_type(8)));
typedef float  f32x4  __attribute__((ext_vector_type(4)));
typedef unsigned short ushortx8 __attribute__((ext_vector_type(8)));
typedef unsigned short ushortx4 __attribute__((ext_vector_type(4)));

__device__ __forceinline__ float bf2f(unsigned short u) {
    unsigned int t = ((unsigned int)u) << 16;
    return __builtin_bit_cast(float, t);
}
__device__ __forceinline__ unsigned short f2bf(float f) {
    __hip_bfloat16 hb = __float2bfloat16(f);
    return *reinterpret_cast<unsigned short*>(&hb);
}

// ---------------- LayerNorm (288 blocks) + weight prepack (36 blocks) ------
__global__ void ln_prepack_kernel(const float* __restrict__ x,
                                  const float* __restrict__ lnw,
                                  const float* __restrict__ lnb,
                                  unsigned short* __restrict__ xnb,
                                  const float* __restrict__ dw,
                                  const float* __restrict__ fw,
                                  const float* __restrict__ offw,
                                  const float* __restrict__ maskw,
                                  unsigned short* __restrict__ wpack,
                                  unsigned short* __restrict__ wpf,
                                  unsigned short* __restrict__ wpc) {
    if (blockIdx.x < 288) {
        int p = blockIdx.x * 256 + threadIdx.x;
        int b = p / HW_, pix = p % HW_;
        const float* xb = x + (size_t)b * C_ * HW_ + pix;
        float v[C_];
        float s = 0.f, s2 = 0.f;
        #pragma unroll
        for (int c = 0; c < C_; ++c) {
            v[c] = xb[(size_t)c * HW_];
            s += v[c]; s2 += v[c] * v[c];
        }
        float mu  = s * (1.0f / C_);
        float var = s2 * (1.0f / C_) - mu * mu;
        float inv = rsqrtf(var + 1e-5f);
        unsigned short* zb = xnb + (size_t)p * 64;
        #pragma unroll
        for (int g = 0; g < 8; ++g) {
            ushortx8 st;
            #pragma unroll
            for (int j = 0; j < 8; ++j) {
                int c = g * 8 + j;
                st[j] = f2bf((v[c] - mu) * inv * lnw[c] + lnb[c]);
            }
            *reinterpret_cast<ushortx8*>(zb + g * 8) = st;
        }
        return;
    }
    const int n1 = 4 * KSTEPS_ * 64 * 8;
    const int n2 = 4 * KSTEPS_ * 64 * 8;
    const int n3 = 2 * KSTEPS_ * 64 * 8;
    int gid = (blockIdx.x - 288) * 256 + threadIdx.x;
    int nth = 36 * 256;
    for (int idx = gid; idx < n1 + n2 + n3; idx += nth) {
        int which = (idx < n1) ? 0 : (idx < n1 + n2 ? 1 : 2);
        int rem = idx - (which == 0 ? 0 : (which == 1 ? n1 : n1 + n2));
        int j = rem & 7;
        int l = (rem >> 3) & 63;
        int rest = rem >> 9;
        int s = rest % KSTEPS_;
        int t = rest / KSTEPS_;
        int oc = t * 16 + (l & 15);
        int ck = s * 32 + (l >> 4) * 8 + j;
        int k = ck >> 6, c = ck & 63;
        float v;
        if (which == 0) {
            v = dw[(size_t)oc * CK_ + c * 9 + k];
        } else if (which == 1) {
            v = fw[(size_t)oc * CK_ + c * 9 + k];
        } else {
            v = (oc < 18) ? offw[(size_t)oc * CK_ + c * 9 + k]
              : (oc < 27) ? maskw[(size_t)(oc - 18) * CK_ + c * 9 + k]
              : 0.f;
        }
        unsigned short u = f2bf(v);
        if (which == 0) wpack[rem] = u;
        else if (which == 1) wpf[rem] = u;
        else wpc[rem] = u;
    }
}

// ---------------- merged conv27 + deformable conv ---------------------------
// block = 2 waves over 2 rows x 16 cols.
// Phase 1: ROW-split conv27 (wave w -> row h0+w, full K). Barrier.
// Phase 2: quarter-balanced tap split (9 gather-quarters per wave),
//          straight-line tapbody (compiler-scheduled);
//          LDS accumulator exchange at the end.
// som: [32][32] with per-row col rotation (col+4*(pq&7))&31 -> 20480 B LDS
//      total => 8 blocks/CU, 2-way max bank alias on om reads.
__global__ void __launch_bounds__(128) dc_mfma(
        const unsigned short* __restrict__ xnb,   // NHWC
        const unsigned short* __restrict__ wpc,
        const float* __restrict__ offb, const float* __restrict__ maskb,
        const unsigned short* __restrict__ wpack,
        const float* __restrict__ db,
        unsigned short* __restrict__ xdefb) {     // NHWC
    __shared__ ushortx8 win[WCHUNKS_];           // 16128 B (reused as exchange)
    __shared__ alignas(16) float som[32][32];    // 4096 B, rotated columns
    int tid  = threadIdx.x;
    int wave = tid >> 6;
    int lane = tid & 63;
    int bid  = blockIdx.x;
    int rg   = bid % (H_ / 2);
    int rest = bid / (H_ / 2);
    int tx   = rest % TX_;
    int b    = rest / TX_;
    int pq = lane & 15;
    int kchunk = lane >> 4;
    int h0 = rg * 2;
    int w0 = tx * 16, w = w0 + pq;
    int rot = (pq & 7) * 4;              // som column rotation for this lane

    const unsigned short* xb = xnb + (size_t)b * HW_ * 64;

    // ---- stage shared window rows h0-2..h0+3, cols w0-2..w0+18 ----
    #pragma unroll
    for (int i = 0; i < 8; ++i) {
        int idx = i * 128 + tid;
        if (idx < WCHUNKS_) {
            int r    = idx / (WCOLS_ * 8);
            int rem2 = idx - r * (WCOLS_ * 8);
            int c    = rem2 >> 3;
            int seg  = rem2 & 7;
            int gy = min(max(h0 - 2 + r, 0), H_ - 1);
            int gx = min(max(w0 - 2 + c, 0), W_ - 1);
            ushortx8 v = *reinterpret_cast<const ushortx8*>(
                xb + ((size_t)(gy * W_ + gx) * 64 + seg * 8));
            win[(r * WCOLS_ + c) * 8 + (seg ^ (c & 7))] = v;
        }
    }
    __syncthreads();

    // ---- phase 1: conv27, row-split (wave w -> row h0+w, full K) ----
    {
        int hp = h0 + wave;
        f32x4 cacc[2];
        cacc[0] = f32x4{0.f, 0.f, 0.f, 0.f};
        cacc[1] = f32x4{0.f, 0.f, 0.f, 0.f};
        #pragma unroll
        for (int s = 0; s < KSTEPS_; ++s) {
            const int k = s >> 1;
            const int dy = k / 3 - 1, dxk = k % 3 - 1;
            int wc = pq + dxk + 2;
            int sidx = ((s & 1) * 4 + kchunk) ^ (wc & 7);
            bool ok = ((unsigned)(hp + dy) < (unsigned)H_) &&
                      ((unsigned)(w + dxk) < (unsigned)W_);
            int wr = wave + dy + 2;
            ushortx8 u = win[(wr * WCOLS_ + wc) * 8 + sidx];
            if (!ok) u = ushortx8{0, 0, 0, 0, 0, 0, 0, 0};
            bf16x8 bv = __builtin_bit_cast(bf16x8, u);
            #pragma unroll
            for (int t = 0; t < 2; ++t) {
                bf16x8 afrag = *reinterpret_cast<const bf16x8*>(
                    wpc + ((size_t)(t * KSTEPS_ + s) * 64 + lane) * 8);
                cacc[t] = __builtin_amdgcn_mfma_f32_16x16x32_bf16(afrag, bv, cacc[t], 0, 0, 0);
            }
        }
        // bias / sigmoid -> som transpose slice (rotated columns)
        #pragma unroll
        for (int t = 0; t < 2; ++t) {
            f32x4 sv;
            #pragma unroll
            for (int r = 0; r < 4; ++r) {
                int oc = t * 16 + kchunk * 4 + r;
                float a = cacc[t][r];
                if (oc < 18)      sv[r] = a + offb[oc];
                else if (oc < 27) sv[r] = 1.f / (1.f + expf(-(a + maskb[oc - 18])));
                else              sv[r] = 0.f;
            }
            int col = (t * 16 + kchunk * 4 + rot) & 31;   // base <= 28, no wrap
            *reinterpret_cast<f32x4*>(&som[wave * 16 + pq][col]) = sv;
        }
    }
    __syncthreads();   // cross-wave som visibility

    // ---- phase 2: quarter-balanced tap split, straight-line tapbody ----
    f32x4 acc[2][4];
    #pragma unroll
    for (int pg = 0; pg < 2; ++pg)
        #pragma unroll
        for (int t = 0; t < 4; ++t) acc[pg][t] = f32x4{0.f, 0.f, 0.f, 0.f};

    auto taprow = [&](int k, int pg) {
        int hp = h0 + pg;
        const float* om = som[pg * 16 + pq];
        float dy = om[(2 * k + rot) & 31];
        float dx = om[(2 * k + 1 + rot) & 31];
        float m  = om[(18 + k + rot) & 31];
        float py = dy + (float)(hp - 1 + k / 3);
        float px = dx + (float)(w - 1 + k % 3);
        float fy = floorf(py), fx = floorf(px);
        float ly = py - fy, lx = px - fx;
        int y0 = (int)fy, x0 = (int)fx;
        int y1 = y0 + 1, x1 = x0 + 1;
        bool oky0 = (unsigned)y0 < (unsigned)H_;
        bool oky1 = (unsigned)y1 < (unsigned)H_;
        bool okx0 = (unsigned)x0 < (unsigned)W_;
        bool okx1 = (unsigned)x1 < (unsigned)W_;
        float q[4];
        q[0] = (oky0 && okx0) ? (1.f - ly) * (1.f - lx) * m : 0.f;
        q[1] = (oky0 && okx1) ? (1.f - ly) * lx * m : 0.f;
        q[2] = (oky1 && okx0) ? ly * (1.f - lx) * m : 0.f;
        q[3] = (oky1 && okx1) ? ly * lx * m : 0.f;
        int wr0 = y0 - (h0 - 2), wr1 = y1 - (h0 - 2);
        int wc0 = x0 - (w0 - 2), wc1 = x1 - (w0 - 2);
        bool inr0 = (unsigned)wr0 < (unsigned)WROWS_;
        bool inr1 = (unsigned)wr1 < (unsigned)WROWS_;
        bool inc0 = (unsigned)wc0 < (unsigned)WCOLS_;
        bool inc1 = (unsigned)wc1 < (unsigned)WCOLS_;
        bool in[4];
        in[0] = inr0 && inc0; in[1] = inr0 && inc1;
        in[2] = inr1 && inc0; in[3] = inr1 && inc1;
        int swr0 = min(max(wr0, 0), WROWS_ - 1), swr1 = min(max(wr1, 0), WROWS_ - 1);
        int swc0 = min(max(wc0, 0), WCOLS_ - 1), swc1 = min(max(wc1, 0), WCOLS_ - 1);
        int cb[4], sx[4];
        cb[0] = (swr0 * WCOLS_ + swc0) * 8; sx[0] = swc0 & 7;
        cb[1] = (swr0 * WCOLS_ + swc1) * 8; sx[1] = swc1 & 7;
        cb[2] = (swr1 * WCOLS_ + swc0) * 8; sx[2] = swc0 & 7;
        cb[3] = (swr1 * WCOLS_ + swc1) * 8; sx[3] = swc1 & 7;
        int cy0 = min(max(y0, 0), H_ - 1), cy1 = min(max(y1, 0), H_ - 1);
        int cx0 = min(max(x0, 0), W_ - 1), cx1 = min(max(x1, 0), W_ - 1);
        int ga[4];
        ga[0] = cy0 * W_ + cx0; ga[1] = cy0 * W_ + cx1;
        ga[2] = cy1 * W_ + cx0; ga[3] = cy1 * W_ + cx1;

        #pragma unroll
        for (int half = 0; half < 2; ++half) {
            int s = k * 2 + half;
            int seg = half * 4 + kchunk;
            int cbg = half * 32 + kchunk * 8;
            ushortx8 v[4];
            #pragma unroll
            for (int c = 0; c < 4; ++c) v[c] = win[cb[c] + (seg ^ sx[c])];
            #pragma unroll
            for (int c = 0; c < 4; ++c)
                if (q[c] != 0.f && !in[c])
                    v[c] = *reinterpret_cast<const ushortx8*>(
                        xb + ((size_t)ga[c] * 64 + cbg));
            union { unsigned short u[8]; bf16x8 v; } bu;
            #pragma unroll
            for (int j = 0; j < 8; ++j) {
                float a = q[0] * bf2f(v[0][j]) + q[1] * bf2f(v[1][j])
                        + q[2] * bf2f(v[2][j]) + q[3] * bf2f(v[3][j]);
                bu.u[j] = f2bf(a);
            }
            #pragma unroll
            for (int t = 0; t < 4; ++t) {
                bf16x8 afr = *reinterpret_cast<const bf16x8*>(
                    wpack + ((size_t)(t * KSTEPS_ + s) * 64 + lane) * 8);
                acc[pg][t] = __builtin_amdgcn_mfma_f32_16x16x32_bf16(
                    afr, bu.v, acc[pg][t], 0, 0, 0);
            }
        }
    };

    if (wave == 0) {   // 9 quarters: taps 0-3 both rows + tap 4 row 0
        taprow(0, 0); taprow(0, 1);
        taprow(1, 0); taprow(1, 1);
        taprow(2, 0); taprow(2, 1);
        taprow(3, 0); taprow(3, 1);
        taprow(4, 0);
    } else {           // 9 quarters: tap 4 row 1 + taps 5-8 both rows
        taprow(4, 1);
        taprow(5, 0); taprow(5, 1);
        taprow(6, 0); taprow(6, 1);
        taprow(7, 0); taprow(7, 1);
        taprow(8, 0); taprow(8, 1);
    }

    // ---- cross-wave accumulator exchange (win reused; 17-pad) ----
    __syncthreads();
    float* red = reinterpret_cast<float*>(win);
    {
        float* slot = red + (wave * 64 + lane) * 17;
        if (wave == 0) {
            #pragma unroll
            for (int t = 0; t < 4; ++t)
                #pragma unroll
                for (int r = 0; r < 4; ++r) slot[t * 4 + r] = acc[1][t][r];
        } else {
            #pragma unroll
            for (int t = 0; t < 4; ++t)
                #pragma unroll
                for (int r = 0; r < 4; ++r) slot[t * 4 + r] = acc[0][t][r];
        }
    }
    __syncthreads();
    {
        const float* pslot = red + ((1 - wave) * 64 + lane) * 17;
        int hp = h0 + wave;
        unsigned short* zb = xdefb + ((size_t)(b * HW_ + hp * W_ + w)) * 64;
        if (wave == 0) {
            #pragma unroll
            for (int t = 0; t < 4; ++t) {
                ushortx4 st;
                #pragma unroll
                for (int r = 0; r < 4; ++r) {
                    int oc = t * 16 + kchunk * 4 + r;
                    st[r] = f2bf(acc[0][t][r] + pslot[t * 4 + r] + db[oc]);
                }
                *reinterpret_cast<ushortx4*>(zb + t * 16 + kchunk * 4) = st;
            }
        } else {
            #pragma unroll
            for (int t = 0; t < 4; ++t) {
                ushortx4 st;
                #pragma unroll
                for (int r = 0; r < 4; ++r) {
                    int oc = t * 16 + kchunk * 4 + r;
                    st[r] = f2bf(acc[1][t][r] + pslot[t * 4 + r] + db[oc]);
                }
                *reinterpret_cast<ushortx4*>(zb + t * 16 + kchunk * 4) = st;
            }
        }
    }
}

// ---------------- fusion conv, K-split across 2 waves ----------------------
__global__ void __launch_bounds__(128) fuse_mfma(
        const unsigned short* __restrict__ xdefb,  // NHWC
        const unsigned short* __restrict__ wpf,
        const float* __restrict__ fb,
        const float* __restrict__ premask,
        const float* __restrict__ xin,             // NCHW
        float* __restrict__ out) {                 // NCHW
    __shared__ ushortx8 fwin[FWCHUNKS_];  // 9216 B (reused as exchange buf)
    int tid  = threadIdx.x;
    int wave = tid >> 6;
    int lane = tid & 63;
    int bid  = blockIdx.x;
    int rg   = bid % (H_ / 2);
    int rest = bid / (H_ / 2);
    int tx   = rest % TX_;
    int b    = rest / TX_;
    int pq = lane & 15;
    int kchunk = lane >> 4;
    int h0 = rg * 2;
    int w0 = tx * 16, w = w0 + pq;

    const unsigned short* xb = xdefb + (size_t)b * HW_ * 64;

    #pragma unroll
    for (int i = 0; i < 5; ++i) {
        int idx = i * 128 + tid;
        if (idx < FWCHUNKS_) {
            int r    = idx / (FWCOLS_ * 8);
            int rem2 = idx - r * (FWCOLS_ * 8);
            int c    = rem2 >> 3;
            int seg  = rem2 & 7;
            int gy = min(max(h0 - 1 + r, 0), H_ - 1);
            int gx = min(max(w0 - 1 + c, 0), W_ - 1);
            ushortx8 v = *reinterpret_cast<const ushortx8*>(
                xb + ((size_t)(gy * W_ + gx) * 64 + seg * 8));
            fwin[(r * FWCOLS_ + c) * 8 + (seg ^ (c & 7))] = v;
        }
    }
    __syncthreads();

    f32x4 acc[2][4];
    #pragma unroll
    for (int pg = 0; pg < 2; ++pg)
        #pragma unroll
        for (int t = 0; t < 4; ++t) acc[pg][t] = f32x4{0.f, 0.f, 0.f, 0.f};

    auto stepbody = [&](int s) {
        const int k = s >> 1;
        const int dy = k / 3 - 1, dxk = k % 3 - 1;
        int wc = pq + dxk + 1;
        int sidx = ((s & 1) * 4 + kchunk) ^ (wc & 7);
        bf16x8 af[4];
        #pragma unroll
        for (int t = 0; t < 4; ++t)
            af[t] = *reinterpret_cast<const bf16x8*>(
                wpf + ((size_t)(t * KSTEPS_ + s) * 64 + lane) * 8);
        #pragma unroll
        for (int pg = 0; pg < 2; ++pg) {
            int hp = h0 + pg;
            bool ok = ((unsigned)(hp + dy) < (unsigned)H_) &&
                      ((unsigned)(w + dxk) < (unsigned)W_);
            int wr = pg + dy + 1;
            ushortx8 u = fwin[(wr * FWCOLS_ + wc) * 8 + sidx];
            if (!ok) u = ushortx8{0, 0, 0, 0, 0, 0, 0, 0};
            bf16x8 bv = __builtin_bit_cast(bf16x8, u);
            #pragma unroll
            for (int t = 0; t < 4; ++t)
                acc[pg][t] = __builtin_amdgcn_mfma_f32_16x16x32_bf16(af[t], bv, acc[pg][t], 0, 0, 0);
        }
    };

    if (wave == 0) {
        stepbody(0); stepbody(1); stepbody(2); stepbody(3); stepbody(4);
        stepbody(5); stepbody(6); stepbody(7); stepbody(8);
    } else {
        stepbody(9); stepbody(10); stepbody(11); stepbody(12); stepbody(13);
        stepbody(14); stepbody(15); stepbody(16); stepbody(17);
    }

    __syncthreads();
    float* red = reinterpret_cast<float*>(fwin);
    {
        float* slot = red + (wave * 64 + lane) * 17;
        if (wave == 0) {
            #pragma unroll
            for (int t = 0; t < 4; ++t)
                #pragma unroll
                for (int r = 0; r < 4; ++r) slot[t * 4 + r] = acc[1][t][r];
        } else {
            #pragma unroll
            for (int t = 0; t < 4; ++t)
                #pragma unroll
                for (int r = 0; r < 4; ++r) slot[t * 4 + r] = acc[0][t][r];
        }
    }
    __syncthreads();
    {
        const float* pslot = red + ((1 - wave) * 64 + lane) * 17;
        int hp = h0 + wave;
        int pix = hp * W_ + w;
        float pm = premask[(size_t)b * HW_ + pix];
        if (wave == 0) {
            #pragma unroll
            for (int t = 0; t < 4; ++t) {
                #pragma unroll
                for (int r = 0; r < 4; ++r) {
                    int oc = t * 16 + kchunk * 4 + r;
                    size_t oidx = ((size_t)b * C_ + oc) * HW_ + pix;
                    float a = acc[0][t][r] + pslot[t * 4 + r] + fb[oc];
                    out[oidx] = a * pm + xin[oidx] * (1.f - pm);
                }
            }
        } else {
            #pragma unroll
            for (int t = 0; t < 4; ++t) {
                #pragma unroll
                for (int r = 0; r < 4; ++r) {
                    int oc = t * 16 + kchunk * 4 + r;
                    size_t oidx = ((size_t)b * C_ + oc) * HW_ + pix;
                    float a = acc[1][t][r] + pslot[t * 4 + r] + fb[oc];
                    out[oidx] = a * pm + xin[oidx] * (1.f - pm);
                }
            }
        }
    }
}

extern "C" void kernel_launch(void* const* d_in, const int* in_sizes, int n_in,
                              void* d_out, int out_size, void* d_ws, size_t ws_size,
                              hipStream_t stream) {
    const float* x       = (const float*)d_in[0];
    const float* premask = (const float*)d_in[1];
    const float* lnw     = (const float*)d_in[2];
    const float* lnb     = (const float*)d_in[3];
    const float* offw    = (const float*)d_in[4];
    const float* offb    = (const float*)d_in[5];
    const float* maskw   = (const float*)d_in[6];
    const float* maskb   = (const float*)d_in[7];
    const float* dw      = (const float*)d_in[8];
    const float* db      = (const float*)d_in[9];
    const float* fw      = (const float*)d_in[10];
    const float* fb      = (const float*)d_in[11];
    float* out = (float*)d_out;

    char* ws = (char*)d_ws;
    unsigned short* xnb   = (unsigned short*)ws;  ws += sizeof(short) * (size_t)BHW_ * 64;
    unsigned short* xdefb = (unsigned short*)ws;  ws += sizeof(short) * (size_t)BHW_ * 64;
    unsigned short* wpack = (unsigned short*)ws;  ws += sizeof(short) * 4 * KSTEPS_ * 64 * 8;
    unsigned short* wpf   = (unsigned short*)ws;  ws += sizeof(short) * 4 * KSTEPS_ * 64 * 8;
    unsigned short* wpc   = (unsigned short*)ws;  ws += sizeof(short) * 2 * KSTEPS_ * 64 * 8;

    const int grid = B_ * TX_ * (H_ / 2);   // 2304 two-wave blocks

    ln_prepack_kernel<<<288 + 36, 256, 0, stream>>>(
        x, lnw, lnb, xnb, dw, fw, offw, maskw, wpack, wpf, wpc);
    dc_mfma<<<grid, 128, 0, stream>>>(
        xnb, wpc, offb, maskb, wpack, db, xdefb);
    fuse_mfma<<<grid, 128, 0, stream>>>(xdefb, wpf, fb, premask, x, out);
}

// Round 20
// 71.747 us; speedup vs baseline: 1.1155x; 1.0038x over previous
//
#include <hip/hip_runtime.h>
#include <hip/hip_bf16.h>
#include <math.h>

#define B_ 2
#define C_ 64
#define H_ 192
#define W_ 192
#define HW_ (H_*W_)
#define BHW_ (B_*HW_)
#define KK_ 9
#define CK_ (C_*KK_)      // 576
#define KSTEPS_ (CK_/32)  // 18
#define TX_ 12            // W_/16 column tiles
#define WROWS_ 6          // dc window rows (h0-2 .. h0+3)
#define WCOLS_ 21         // dc window cols (w0-2 .. w0+18)
#define WCHUNKS_ (WROWS_*WCOLS_*8)     // 1008
#define FWROWS_ 4         // fuse window rows (h0-1 .. h0+2)
#define FWCOLS_ 18        // fuse window cols (w0-1 .. w0+16)
#define FWCHUNKS_ (FWROWS_*FWCOLS_*8)  // 576

typedef __bf16 bf16x8 __attribute__((ext_vector_type(8)));
typedef float  f32x4  __attribute__((ext_vector_type(4)));
typedef float  f32x2  __attribute__((ext_vector_type(2)));
typedef unsigned short ushortx8 __attribute__((ext_vector_type(8)));
typedef unsigned short ushortx4 __attribute__((ext_vector_type(4)));

__device__ __forceinline__ float bf2f(unsigned short u) {
    unsigned int t = ((unsigned int)u) << 16;
    return __builtin_bit_cast(float, t);
}
__device__ __forceinline__ unsigned short f2bf(float f) {
    __hip_bfloat16 hb = __float2bfloat16(f);
    return *reinterpret_cast<unsigned short*>(&hb);
}

// ---------------- LayerNorm (144 blocks, 2 px/thread) + prepack (36) -------
__global__ void ln_prepack_kernel(const float* __restrict__ x,
                                  const float* __restrict__ lnw,
                                  const float* __restrict__ lnb,
                                  unsigned short* __restrict__ xnb,
                                  const float* __restrict__ dw,
                                  const float* __restrict__ fw,
                                  const float* __restrict__ offw,
                                  const float* __restrict__ maskw,
                                  unsigned short* __restrict__ wpack,
                                  unsigned short* __restrict__ wpf,
                                  unsigned short* __restrict__ wpc) {
    if (blockIdx.x < 144) {
        int p0 = (blockIdx.x * 256 + threadIdx.x) * 2;   // even pixel pair
        int b = p0 / HW_, pix = p0 % HW_;                // pair never crosses b (HW even)
        const float* xb = x + (size_t)b * C_ * HW_ + pix;
        f32x2 v[C_];
        float s0 = 0.f, s20 = 0.f, s1 = 0.f, s21 = 0.f;
        #pragma unroll
        for (int c = 0; c < C_; ++c) {
            v[c] = *reinterpret_cast<const f32x2*>(xb + (size_t)c * HW_);
            s0 += v[c][0]; s20 += v[c][0] * v[c][0];
            s1 += v[c][1]; s21 += v[c][1] * v[c][1];
        }
        float mu0  = s0 * (1.0f / C_);
        float var0 = s20 * (1.0f / C_) - mu0 * mu0;
        float inv0 = rsqrtf(var0 + 1e-5f);
        float mu1  = s1 * (1.0f / C_);
        float var1 = s21 * (1.0f / C_) - mu1 * mu1;
        float inv1 = rsqrtf(var1 + 1e-5f);
        unsigned short* zb = xnb + (size_t)p0 * 64;
        #pragma unroll
        for (int g = 0; g < 8; ++g) {
            ushortx8 st0, st1;
            #pragma unroll
            for (int j = 0; j < 8; ++j) {
                int c = g * 8 + j;
                float lw = lnw[c], lb = lnb[c];
                st0[j] = f2bf((v[c][0] - mu0) * inv0 * lw + lb);
                st1[j] = f2bf((v[c][1] - mu1) * inv1 * lw + lb);
            }
            *reinterpret_cast<ushortx8*>(zb + g * 8) = st0;
            *reinterpret_cast<ushortx8*>(zb + 64 + g * 8) = st1;
        }
        return;
    }
    const int n1 = 4 * KSTEPS_ * 64 * 8;
    const int n2 = 4 * KSTEPS_ * 64 * 8;
    const int n3 = 2 * KSTEPS_ * 64 * 8;
    int gid = (blockIdx.x - 144) * 256 + threadIdx.x;
    int nth = 36 * 256;
    for (int idx = gid; idx < n1 + n2 + n3; idx += nth) {
        int which = (idx < n1) ? 0 : (idx < n1 + n2 ? 1 : 2);
        int rem = idx - (which == 0 ? 0 : (which == 1 ? n1 : n1 + n2));
        int j = rem & 7;
        int l = (rem >> 3) & 63;
        int rest = rem >> 9;
        int s = rest % KSTEPS_;
        int t = rest / KSTEPS_;
        int oc = t * 16 + (l & 15);
        int ck = s * 32 + (l >> 4) * 8 + j;
        int k = ck >> 6, c = ck & 63;
        float v;
        if (which == 0) {
            v = dw[(size_t)oc * CK_ + c * 9 + k];
        } else if (which == 1) {
            v = fw[(size_t)oc * CK_ + c * 9 + k];
        } else {
            v = (oc < 18) ? offw[(size_t)oc * CK_ + c * 9 + k]
              : (oc < 27) ? maskw[(size_t)(oc - 18) * CK_ + c * 9 + k]
              : 0.f;
        }
        unsigned short u = f2bf(v);
        if (which == 0) wpack[rem] = u;
        else if (which == 1) wpf[rem] = u;
        else wpc[rem] = u;
    }
}

// ---------------- merged conv27 + deformable conv ---------------------------
// block = 2 waves over 2 rows x 16 cols.
// Phase 1: ROW-split conv27 (wave w -> row h0+w, full K). Barrier.
// Phase 2: quarter-balanced tap split (9 gather-quarters per wave),
//          straight-line tapbody (compiler-scheduled);
//          LDS accumulator exchange at the end.
__global__ void __launch_bounds__(128) dc_mfma(
        const unsigned short* __restrict__ xnb,   // NHWC
        const unsigned short* __restrict__ wpc,
        const float* __restrict__ offb, const float* __restrict__ maskb,
        const unsigned short* __restrict__ wpack,
        const float* __restrict__ db,
        unsigned short* __restrict__ xdefb) {     // NHWC
    __shared__ ushortx8 win[WCHUNKS_];           // 16128 B (reused as exchange)
    __shared__ alignas(16) float som[32][32];    // 4096 B, rotated columns
    int tid  = threadIdx.x;
    int wave = tid >> 6;
    int lane = tid & 63;
    int bid  = blockIdx.x;
    int rg   = bid % (H_ / 2);
    int rest = bid / (H_ / 2);
    int tx   = rest % TX_;
    int b    = rest / TX_;
    int pq = lane & 15;
    int kchunk = lane >> 4;
    int h0 = rg * 2;
    int w0 = tx * 16, w = w0 + pq;
    int rot = (pq & 7) * 4;              // som column rotation for this lane

    const unsigned short* xb = xnb + (size_t)b * HW_ * 64;

    // ---- stage shared window rows h0-2..h0+3, cols w0-2..w0+18 ----
    #pragma unroll
    for (int i = 0; i < 8; ++i) {
        int idx = i * 128 + tid;
        if (idx < WCHUNKS_) {
            int r    = idx / (WCOLS_ * 8);
            int rem2 = idx - r * (WCOLS_ * 8);
            int c    = rem2 >> 3;
            int seg  = rem2 & 7;
            int gy = min(max(h0 - 2 + r, 0), H_ - 1);
            int gx = min(max(w0 - 2 + c, 0), W_ - 1);
            ushortx8 v = *reinterpret_cast<const ushortx8*>(
                xb + ((size_t)(gy * W_ + gx) * 64 + seg * 8));
            win[(r * WCOLS_ + c) * 8 + (seg ^ (c & 7))] = v;
        }
    }
    __syncthreads();

    // ---- phase 1: conv27, row-split (wave w -> row h0+w, full K) ----
    {
        int hp = h0 + wave;
        f32x4 cacc[2];
        cacc[0] = f32x4{0.f, 0.f, 0.f, 0.f};
        cacc[1] = f32x4{0.f, 0.f, 0.f, 0.f};
        #pragma unroll
        for (int s = 0; s < KSTEPS_; ++s) {
            const int k = s >> 1;
            const int dy = k / 3 - 1, dxk = k % 3 - 1;
            int wc = pq + dxk + 2;
            int sidx = ((s & 1) * 4 + kchunk) ^ (wc & 7);
            bool ok = ((unsigned)(hp + dy) < (unsigned)H_) &&
                      ((unsigned)(w + dxk) < (unsigned)W_);
            int wr = wave + dy + 2;
            ushortx8 u = win[(wr * WCOLS_ + wc) * 8 + sidx];
            if (!ok) u = ushortx8{0, 0, 0, 0, 0, 0, 0, 0};
            bf16x8 bv = __builtin_bit_cast(bf16x8, u);
            #pragma unroll
            for (int t = 0; t < 2; ++t) {
                bf16x8 afrag = *reinterpret_cast<const bf16x8*>(
                    wpc + ((size_t)(t * KSTEPS_ + s) * 64 + lane) * 8);
                cacc[t] = __builtin_amdgcn_mfma_f32_16x16x32_bf16(afrag, bv, cacc[t], 0, 0, 0);
            }
        }
        // bias / sigmoid -> som transpose slice (rotated columns)
        #pragma unroll
        for (int t = 0; t < 2; ++t) {
            f32x4 sv;
            #pragma unroll
            for (int r = 0; r < 4; ++r) {
                int oc = t * 16 + kchunk * 4 + r;
                float a = cacc[t][r];
                if (oc < 18)      sv[r] = a + offb[oc];
                else if (oc < 27) sv[r] = 1.f / (1.f + expf(-(a + maskb[oc - 18])));
                else              sv[r] = 0.f;
            }
            int col = (t * 16 + kchunk * 4 + rot) & 31;   // base <= 28, no wrap
            *reinterpret_cast<f32x4*>(&som[wave * 16 + pq][col]) = sv;
        }
    }
    __syncthreads();   // cross-wave som visibility

    // ---- phase 2: quarter-balanced tap split, straight-line tapbody ----
    f32x4 acc[2][4];
    #pragma unroll
    for (int pg = 0; pg < 2; ++pg)
        #pragma unroll
        for (int t = 0; t < 4; ++t) acc[pg][t] = f32x4{0.f, 0.f, 0.f, 0.f};

    auto taprow = [&](int k, int pg) {
        int hp = h0 + pg;
        const float* om = som[pg * 16 + pq];
        float dy = om[(2 * k + rot) & 31];
        float dx = om[(2 * k + 1 + rot) & 31];
        float m  = om[(18 + k + rot) & 31];
        float py = dy + (float)(hp - 1 + k / 3);
        float px = dx + (float)(w - 1 + k % 3);
        float fy = floorf(py), fx = floorf(px);
        float ly = py - fy, lx = px - fx;
        int y0 = (int)fy, x0 = (int)fx;
        int y1 = y0 + 1, x1 = x0 + 1;
        bool oky0 = (unsigned)y0 < (unsigned)H_;
        bool oky1 = (unsigned)y1 < (unsigned)H_;
        bool okx0 = (unsigned)x0 < (unsigned)W_;
        bool okx1 = (unsigned)x1 < (unsigned)W_;
        float q[4];
        q[0] = (oky0 && okx0) ? (1.f - ly) * (1.f - lx) * m : 0.f;
        q[1] = (oky0 && okx1) ? (1.f - ly) * lx * m : 0.f;
        q[2] = (oky1 && okx0) ? ly * (1.f - lx) * m : 0.f;
        q[3] = (oky1 && okx1) ? ly * lx * m : 0.f;
        int wr0 = y0 - (h0 - 2), wr1 = y1 - (h0 - 2);
        int wc0 = x0 - (w0 - 2), wc1 = x1 - (w0 - 2);
        bool inr0 = (unsigned)wr0 < (unsigned)WROWS_;
        bool inr1 = (unsigned)wr1 < (unsigned)WROWS_;
        bool inc0 = (unsigned)wc0 < (unsigned)WCOLS_;
        bool inc1 = (unsigned)wc1 < (unsigned)WCOLS_;
        bool in[4];
        in[0] = inr0 && inc0; in[1] = inr0 && inc1;
        in[2] = inr1 && inc0; in[3] = inr1 && inc1;
        int swr0 = min(max(wr0, 0), WROWS_ - 1), swr1 = min(max(wr1, 0), WROWS_ - 1);
        int swc0 = min(max(wc0, 0), WCOLS_ - 1), swc1 = min(max(wc1, 0), WCOLS_ - 1);
        int cb[4], sx[4];
        cb[0] = (swr0 * WCOLS_ + swc0) * 8; sx[0] = swc0 & 7;
        cb[1] = (swr0 * WCOLS_ + swc1) * 8; sx[1] = swc1 & 7;
        cb[2] = (swr1 * WCOLS_ + swc0) * 8; sx[2] = swc0 & 7;
        cb[3] = (swr1 * WCOLS_ + swc1) * 8; sx[3] = swc1 & 7;
        int cy0 = min(max(y0, 0), H_ - 1), cy1 = min(max(y1, 0), H_ - 1);
        int cx0 = min(max(x0, 0), W_ - 1), cx1 = min(max(x1, 0), W_ - 1);
        int ga[4];
        ga[0] = cy0 * W_ + cx0; ga[1] = cy0 * W_ + cx1;
        ga[2] = cy1 * W_ + cx0; ga[3] = cy1 * W_ + cx1;

        #pragma unroll
        for (int half = 0; half < 2; ++half) {
            int s = k * 2 + half;
            int seg = half * 4 + kchunk;
            int cbg = half * 32 + kchunk * 8;
            ushortx8 v[4];
            #pragma unroll
            for (int c = 0; c < 4; ++c) v[c] = win[cb[c] + (seg ^ sx[c])];
            #pragma unroll
            for (int c = 0; c < 4; ++c)
                if (q[c] != 0.f && !in[c])
                    v[c] = *reinterpret_cast<const ushortx8*>(
                        xb + ((size_t)ga[c] * 64 + cbg));
            union { unsigned short u[8]; bf16x8 v; } bu;
            #pragma unroll
            for (int j = 0; j < 8; ++j) {
                float a = q[0] * bf2f(v[0][j]) + q[1] * bf2f(v[1][j])
                        + q[2] * bf2f(v[2][j]) + q[3] * bf2f(v[3][j]);
                bu.u[j] = f2bf(a);
            }
            #pragma unroll
            for (int t = 0; t < 4; ++t) {
                bf16x8 afr = *reinterpret_cast<const bf16x8*>(
                    wpack + ((size_t)(t * KSTEPS_ + s) * 64 + lane) * 8);
                acc[pg][t] = __builtin_amdgcn_mfma_f32_16x16x32_bf16(
                    afr, bu.v, acc[pg][t], 0, 0, 0);
            }
        }
    };

    if (wave == 0) {   // 9 quarters: taps 0-3 both rows + tap 4 row 0
        taprow(0, 0); taprow(0, 1);
        taprow(1, 0); taprow(1, 1);
        taprow(2, 0); taprow(2, 1);
        taprow(3, 0); taprow(3, 1);
        taprow(4, 0);
    } else {           // 9 quarters: tap 4 row 1 + taps 5-8 both rows
        taprow(4, 1);
        taprow(5, 0); taprow(5, 1);
        taprow(6, 0); taprow(6, 1);
        taprow(7, 0); taprow(7, 1);
        taprow(8, 0); taprow(8, 1);
    }

    // ---- cross-wave accumulator exchange (win reused; 17-pad) ----
    __syncthreads();
    float* red = reinterpret_cast<float*>(win);
    {
        float* slot = red + (wave * 64 + lane) * 17;
        if (wave == 0) {
            #pragma unroll
            for (int t = 0; t < 4; ++t)
                #pragma unroll
                for (int r = 0; r < 4; ++r) slot[t * 4 + r] = acc[1][t][r];
        } else {
            #pragma unroll
            for (int t = 0; t < 4; ++t)
                #pragma unroll
                for (int r = 0; r < 4; ++r) slot[t * 4 + r] = acc[0][t][r];
        }
    }
    __syncthreads();
    {
        const float* pslot = red + ((1 - wave) * 64 + lane) * 17;
        int hp = h0 + wave;
        unsigned short* zb = xdefb + ((size_t)(b * HW_ + hp * W_ + w)) * 64;
        if (wave == 0) {
            #pragma unroll
            for (int t = 0; t < 4; ++t) {
                ushortx4 st;
                #pragma unroll
                for (int r = 0; r < 4; ++r) {
                    int oc = t * 16 + kchunk * 4 + r;
                    st[r] = f2bf(acc[0][t][r] + pslot[t * 4 + r] + db[oc]);
                }
                *reinterpret_cast<ushortx4*>(zb + t * 16 + kchunk * 4) = st;
            }
        } else {
            #pragma unroll
            for (int t = 0; t < 4; ++t) {
                ushortx4 st;
                #pragma unroll
                for (int r = 0; r < 4; ++r) {
                    int oc = t * 16 + kchunk * 4 + r;
                    st[r] = f2bf(acc[1][t][r] + pslot[t * 4 + r] + db[oc]);
                }
                *reinterpret_cast<ushortx4*>(zb + t * 16 + kchunk * 4) = st;
            }
        }
    }
}

// ---------------- fusion conv, K-split across 2 waves ----------------------
__global__ void __launch_bounds__(128) fuse_mfma(
        const unsigned short* __restrict__ xdefb,  // NHWC
        const unsigned short* __restrict__ wpf,
        const float* __restrict__ fb,
        const float* __restrict__ premask,
        const float* __restrict__ xin,             // NCHW
        float* __restrict__ out) {                 // NCHW
    __shared__ ushortx8 fwin[FWCHUNKS_];  // 9216 B (reused as exchange buf)
    int tid  = threadIdx.x;
    int wave = tid >> 6;
    int lane = tid & 63;
    int bid  = blockIdx.x;
    int rg   = bid % (H_ / 2);
    int rest = bid / (H_ / 2);
    int tx   = rest % TX_;
    int b    = rest / TX_;
    int pq = lane & 15;
    int kchunk = lane >> 4;
    int h0 = rg * 2;
    int w0 = tx * 16, w = w0 + pq;

    const unsigned short* xb = xdefb + (size_t)b * HW_ * 64;

    #pragma unroll
    for (int i = 0; i < 5; ++i) {
        int idx = i * 128 + tid;
        if (idx < FWCHUNKS_) {
            int r    = idx / (FWCOLS_ * 8);
            int rem2 = idx - r * (FWCOLS_ * 8);
            int c    = rem2 >> 3;
            int seg  = rem2 & 7;
            int gy = min(max(h0 - 1 + r, 0), H_ - 1);
            int gx = min(max(w0 - 1 + c, 0), W_ - 1);
            ushortx8 v = *reinterpret_cast<const ushortx8*>(
                xb + ((size_t)(gy * W_ + gx) * 64 + seg * 8));
            fwin[(r * FWCOLS_ + c) * 8 + (seg ^ (c & 7))] = v;
        }
    }
    __syncthreads();

    f32x4 acc[2][4];
    #pragma unroll
    for (int pg = 0; pg < 2; ++pg)
        #pragma unroll
        for (int t = 0; t < 4; ++t) acc[pg][t] = f32x4{0.f, 0.f, 0.f, 0.f};

    auto stepbody = [&](int s) {
        const int k = s >> 1;
        const int dy = k / 3 - 1, dxk = k % 3 - 1;
        int wc = pq + dxk + 1;
        int sidx = ((s & 1) * 4 + kchunk) ^ (wc & 7);
        bf16x8 af[4];
        #pragma unroll
        for (int t = 0; t < 4; ++t)
            af[t] = *reinterpret_cast<const bf16x8*>(
                wpf + ((size_t)(t * KSTEPS_ + s) * 64 + lane) * 8);
        #pragma unroll
        for (int pg = 0; pg < 2; ++pg) {
            int hp = h0 + pg;
            bool ok = ((unsigned)(hp + dy) < (unsigned)H_) &&
                      ((unsigned)(w + dxk) < (unsigned)W_);
            int wr = pg + dy + 1;
            ushortx8 u = fwin[(wr * FWCOLS_ + wc) * 8 + sidx];
            if (!ok) u = ushortx8{0, 0, 0, 0, 0, 0, 0, 0};
            bf16x8 bv = __builtin_bit_cast(bf16x8, u);
            #pragma unroll
            for (int t = 0; t < 4; ++t)
                acc[pg][t] = __builtin_amdgcn_mfma_f32_16x16x32_bf16(af[t], bv, acc[pg][t], 0, 0, 0);
        }
    };

    if (wave == 0) {
        stepbody(0); stepbody(1); stepbody(2); stepbody(3); stepbody(4);
        stepbody(5); stepbody(6); stepbody(7); stepbody(8);
    } else {
        stepbody(9); stepbody(10); stepbody(11); stepbody(12); stepbody(13);
        stepbody(14); stepbody(15); stepbody(16); stepbody(17);
    }

    __syncthreads();
    float* red = reinterpret_cast<float*>(fwin);
    {
        float* slot = red + (wave * 64 + lane) * 17;
        if (wave == 0) {
            #pragma unroll
            for (int t = 0; t < 4; ++t)
                #pragma unroll
                for (int r = 0; r < 4; ++r) slot[t * 4 + r] = acc[1][t][r];
        } else {
            #pragma unroll
            for (int t = 0; t < 4; ++t)
                #pragma unroll
                for (int r = 0; r < 4; ++r) slot[t * 4 + r] = acc[0][t][r];
        }
    }
    __syncthreads();
    {
        const float* pslot = red + ((1 - wave) * 64 + lane) * 17;
        int hp = h0 + wave;
        int pix = hp * W_ + w;
        float pm = premask[(size_t)b * HW_ + pix];
        if (wave == 0) {
            #pragma unroll
            for (int t = 0; t < 4; ++t) {
                #pragma unroll
                for (int r = 0; r < 4; ++r) {
                    int oc = t * 16 + kchunk * 4 + r;
                    size_t oidx = ((size_t)b * C_ + oc) * HW_ + pix;
                    float a = acc[0][t][r] + pslot[t * 4 + r] + fb[oc];
                    out[oidx] = a * pm + xin[oidx] * (1.f - pm);
                }
            }
        } else {
            #pragma unroll
            for (int t = 0; t < 4; ++t) {
                #pragma unroll
                for (int r = 0; r < 4; ++r) {
                    int oc = t * 16 + kchunk * 4 + r;
                    size_t oidx = ((size_t)b * C_ + oc) * HW_ + pix;
                    float a = acc[1][t][r] + pslot[t * 4 + r] + fb[oc];
                    out[oidx] = a * pm + xin[oidx] * (1.f - pm);
                }
            }
        }
    }
}

extern "C" void kernel_launch(void* const* d_in, const int* in_sizes, int n_in,
                              void* d_out, int out_size, void* d_ws, size_t ws_size,
                              hipStream_t stream) {
    const float* x       = (const float*)d_in[0];
    const float* premask = (const float*)d_in[1];
    const float* lnw     = (const float*)d_in[2];
    const float* lnb     = (const float*)d_in[3];
    const float* offw    = (const float*)d_in[4];
    const float* offb    = (const float*)d_in[5];
    const float* maskw   = (const float*)d_in[6];
    const float* maskb   = (const float*)d_in[7];
    const float* dw      = (const float*)d_in[8];
    const float* db      = (const float*)d_in[9];
    const float* fw      = (const float*)d_in[10];
    const float* fb      = (const float*)d_in[11];
    float* out = (float*)d_out;

    char* ws = (char*)d_ws;
    unsigned short* xnb   = (unsigned short*)ws;  ws += sizeof(short) * (size_t)BHW_ * 64;
    unsigned short* xdefb = (unsigned short*)ws;  ws += sizeof(short) * (size_t)BHW_ * 64;
    unsigned short* wpack = (unsigned short*)ws;  ws += sizeof(short) * 4 * KSTEPS_ * 64 * 8;
    unsigned short* wpf   = (unsigned short*)ws;  ws += sizeof(short) * 4 * KSTEPS_ * 64 * 8;
    unsigned short* wpc   = (unsigned short*)ws;  ws += sizeof(short) * 2 * KSTEPS_ * 64 * 8;

    const int grid = B_ * TX_ * (H_ / 2);   // 2304 two-wave blocks

    ln_prepack_kernel<<<144 + 36, 256, 0, stream>>>(
        x, lnw, lnb, xnb, dw, fw, offw, maskw, wpack, wpf, wpc);
    dc_mfma<<<grid, 128, 0, stream>>>(
        xnb, wpc, offb, maskb, wpack, db, xdefb);
    fuse_mfma<<<grid, 128, 0, stream>>>(xdefb, wpf, fb, premask, x, out);
}